// Round 6
// baseline (1051.110 us; speedup 1.0000x reference)
//
#include <hip/hip_runtime.h>
#include <hip/hip_bf16.h>
#include <stdint.h>

// ---------- helpers ----------
typedef __attribute__((ext_vector_type(8))) short short8v;   // 8 x bf16 bits (4 VGPRs)
typedef __attribute__((ext_vector_type(4))) float f32x4;

__device__ __forceinline__ unsigned short f2bf(float f) {
  unsigned u = __builtin_bit_cast(unsigned, f);
  unsigned r = 0x7fffu + ((u >> 16) & 1u);          // round-to-nearest-even
  return (unsigned short)((u + r) >> 16);
}
__device__ __forceinline__ float bf2f(unsigned short h) {
  unsigned u = ((unsigned)h) << 16;
  return __builtin_bit_cast(float, u);
}
__device__ __forceinline__ void gload_lds16(const void* g, void* l) {
  __builtin_amdgcn_global_load_lds(
      (const __attribute__((address_space(1))) void*)g,
      (__attribute__((address_space(3))) void*)l, 16, 0, 0);
}
#define SBAR  __builtin_amdgcn_s_barrier()
#define SCHED __builtin_amdgcn_sched_barrier(0)

// ---------- split kernels ----------
__global__ __launch_bounds__(256) void split_plain(
    const float4* __restrict__ X, ushort4* __restrict__ H, ushort4* __restrict__ L, int n4) {
  int idx = blockIdx.x * 256 + threadIdx.x;
  if (idx >= n4) return;
  float4 v = X[idx];
  ushort4 h, l;
  h.x = f2bf(v.x); l.x = f2bf(v.x - bf2f(h.x));
  h.y = f2bf(v.y); l.y = f2bf(v.y - bf2f(h.y));
  h.z = f2bf(v.z); l.z = f2bf(v.z - bf2f(h.z));
  h.w = f2bf(v.w); l.w = f2bf(v.w - bf2f(h.w));
  H[idx] = h; L[idx] = l;
}

__global__ __launch_bounds__(256) void split_T(
    const float* __restrict__ W, unsigned short* __restrict__ H,
    unsigned short* __restrict__ L, int Kd, int Nd) {
  __shared__ float tile[32][33];
  const int t = threadIdx.x;
  const int c = t & 31;
  const int r0 = t >> 5;
  const int k0 = blockIdx.y * 32, n0 = blockIdx.x * 32;
#pragma unroll
  for (int i = 0; i < 4; ++i) {
    int r = r0 + i * 8;
    tile[r][c] = W[(size_t)(k0 + r) * Nd + n0 + c];
  }
  __syncthreads();
#pragma unroll
  for (int i = 0; i < 4; ++i) {
    int n = r0 + i * 8;
    float f = tile[c][n];
    unsigned short h = f2bf(f);
    unsigned short l = f2bf(f - bf2f(h));
    size_t o = (size_t)(n0 + n) * Kd + k0 + c;
    H[o] = h; L[o] = l;
  }
}

// ---------- FUSED split GEMM: C = Ah@Bh^T + Ah@Bl^T + Al@Bh^T ----------
// 256x256 tile, BK=32, 2-slot ring. RACE-FIX vs r5: every sub-block is
// {vmcnt(N); SBAR; reads; stage(t+1); MFMA} — each wave certifies its OWN
// staging loads landed BEFORE the barrier releases cross-wave readers
// (vmcnt is per-wave; readers consume other waves' gload_lds output).
// 3 SBAR per 32-K tile; vmcnt never 0 mid-loop.
// EPI 0: fp32 C; 2: split hi/lo bf16.
template<int EPI>
__global__ __launch_bounds__(512, 2) void gemm_fused3(
    const unsigned short* __restrict__ Ah_, const unsigned short* __restrict__ Al_,
    const unsigned short* __restrict__ Bh_, const unsigned short* __restrict__ Bl_,
    int N, int K,
    float* __restrict__ Cf, unsigned short* __restrict__ Ch, unsigned short* __restrict__ Cl) {
  // 2 slots x [Ah|Bh|Bl|Al] x 8192 ush = 65536 ush = 128 KiB
  __shared__ unsigned short lds[65536];
  const int AH = 0, BH = 8192, BL = 16384, AL = 24576;
  const int NT = K >> 5;
  const int wg = blockIdx.x;
  const int sw = ((wg & 7) << 5) | (wg >> 3);     // XCD-bijective (256 wg)
  const int bx = sw & 15, by = sw >> 4;
  const int m0 = by << 8, n0 = bx << 8;

  const int tid = threadIdx.x;
  const int w = tid >> 6, lane = tid & 63;
  const int wr = w >> 2, wc = w & 3;               // wave tile 128x64
  const int lr = lane & 15;
  // read-side swizzle: phys 16B-slot = logical ^ ((row>>1)&3)
  const int phys = (lane >> 4) ^ ((lr >> 1) & 3);
  const int aoff = (wr * 128 + lr) * 32 + phys * 8;   // + m*512
  const int boff = (wc * 64 + lr) * 32 + phys * 8;    // + n*512
  // stage-side: linear LDS dest, inverse-swizzled global source (Rule 21)
  const int rst = tid >> 2;                            // source row 0..127
  const int ssrc = ((tid & 3) ^ ((tid >> 3) & 3)) * 8; // source k-slot (elements)
  const size_t jstep = (size_t)128 * K;

  const unsigned short* gAh = Ah_ + (size_t)(m0 + rst) * K + ssrc;
  const unsigned short* gAl = Al_ + (size_t)(m0 + rst) * K + ssrc;
  const unsigned short* gBh = Bh_ + (size_t)(n0 + rst) * K + ssrc;
  const unsigned short* gBl = Bl_ + (size_t)(n0 + rst) * K + ssrc;

  f32x4 acc[8][4];
#pragma unroll
  for (int m = 0; m < 8; ++m)
#pragma unroll
    for (int n = 0; n < 4; ++n) acc[m][n] = {0.f, 0.f, 0.f, 0.f};

#define STG2(gp, off, slot1, tt) do {                                   \
    const unsigned short* s_ = (gp) + (size_t)(tt) * 32;                \
    gload_lds16(s_, &lds[(slot1) + (off) + (w << 9)]);                  \
    gload_lds16(s_ + jstep, &lds[(slot1) + (off) + 4096 + (w << 9)]);   \
  } while (0)

  // prologue: stage tile 0 into slot 0, order [Ah, Bh, Bl, Al]  (8 ops)
  STG2(gAh, AH, 0, 0);
  STG2(gBh, BH, 0, 0);
  STG2(gBl, BL, 0, 0);
  STG2(gAl, AL, 0, 0);

  for (int t = 0; t < NT; ++t) {
    const int slot = (t & 1) << 15;         // *32768
    const int slot1 = ((t + 1) & 1) << 15;
    const bool st = (t + 1) < NT;
    short8v ahf[8], bhf[4], blf[4], alf[8];
    // ---- block1 (h,h): certify Ah(t),Bh(t); outstanding 8 -> vmcnt(4) ----
    SCHED; asm volatile("s_waitcnt vmcnt(4)"); SBAR; SCHED;
#pragma unroll
    for (int n = 0; n < 4; ++n)
      bhf[n] = *(const short8v*)&lds[slot + BH + boff + n * 512];
#pragma unroll
    for (int m = 0; m < 8; ++m)
      ahf[m] = *(const short8v*)&lds[slot + AH + aoff + m * 512];
    if (st) { STG2(gAh, AH, slot1, t + 1); STG2(gBh, BH, slot1, t + 1); }
    __builtin_amdgcn_s_setprio(1);
#pragma unroll
    for (int m = 0; m < 8; ++m)
#pragma unroll
      for (int n = 0; n < 4; ++n)
        acc[m][n] = __builtin_amdgcn_mfma_f32_16x16x32_bf16(ahf[m], bhf[n], acc[m][n], 0, 0, 0);
    __builtin_amdgcn_s_setprio(0);
    // ---- block2 (h,l): certify Bl(t) ----
    SCHED;
    if (st) { asm volatile("s_waitcnt vmcnt(6)"); }   // [Bl,Al,Ah',Bh'] -> Bl done
    else    { asm volatile("s_waitcnt vmcnt(2)"); }   // [Bl,Al] -> Bl done
    SBAR; SCHED;
#pragma unroll
    for (int n = 0; n < 4; ++n)
      blf[n] = *(const short8v*)&lds[slot + BL + boff + n * 512];
    if (st) { STG2(gBl, BL, slot1, t + 1); }
    __builtin_amdgcn_s_setprio(1);
#pragma unroll
    for (int m = 0; m < 8; ++m)
#pragma unroll
      for (int n = 0; n < 4; ++n)
        acc[m][n] = __builtin_amdgcn_mfma_f32_16x16x32_bf16(ahf[m], blf[n], acc[m][n], 0, 0, 0);
    __builtin_amdgcn_s_setprio(0);
    // ---- block3 (l,h): certify Al(t) ----
    SCHED;
    if (st) { asm volatile("s_waitcnt vmcnt(6)"); }   // [Al,Ah',Bh',Bl'] -> Al done
    else    { asm volatile("s_waitcnt vmcnt(0)"); }   // [Al] -> done
    SBAR; SCHED;
#pragma unroll
    for (int m = 0; m < 8; ++m)
      alf[m] = *(const short8v*)&lds[slot + AL + aoff + m * 512];
    if (st) { STG2(gAl, AL, slot1, t + 1); }
    __builtin_amdgcn_s_setprio(1);
#pragma unroll
    for (int m = 0; m < 8; ++m)
#pragma unroll
      for (int n = 0; n < 4; ++n)
        acc[m][n] = __builtin_amdgcn_mfma_f32_16x16x32_bf16(alf[m], bhf[n], acc[m][n], 0, 0, 0);
    __builtin_amdgcn_s_setprio(0);
    SCHED;
    // no end-of-tile barrier: block1's SBAR of tile t+1 separates the last
    // reads of slot (t-1)&1 from the next writes to it (all waves' block-3
    // MFMAs force the read drain before they can reach that barrier).
  }
#undef STG2

  // epilogue: frag r -> row=(lane>>4)*4+r, col=lane&15  [m89/m91-verified]
  const int crow = m0 + wr * 128 + ((lane >> 4) << 2);
  const int ccol = n0 + wc * 64 + lr;
#pragma unroll
  for (int mi = 0; mi < 8; ++mi)
#pragma unroll
    for (int r = 0; r < 4; ++r) {
      const int row = crow + mi * 16 + r;
#pragma unroll
      for (int n = 0; n < 4; ++n) {
        const int col = ccol + n * 16;
        const float f = acc[mi][n][r];
        const size_t o = (size_t)row * N + col;
        if (EPI == 0) {
          Cf[o] = f;
        } else {
          const unsigned short h = f2bf(f);
          Ch[o] = h;
          Cl[o] = f2bf(f - bf2f(h));
        }
      }
    }
}

// ---------- plain single-pass GEMM (round-2 proven): C = A @ B^T ----------
// 4-deep ring, counted vmcnt 8/4/0 BEFORE the barrier, one SBAR per tile.
// EPI 0: fp32; 1: bf16.
template<int EPI>
__global__ __launch_bounds__(512, 2) void gemm_plain(
    const unsigned short* __restrict__ A, const unsigned short* __restrict__ B,
    int N, int K,
    float* __restrict__ Cf, unsigned short* __restrict__ Ch) {
  __shared__ unsigned short lds[65536];   // 4 slots x (A 8192 + B 8192)
  const int NT = K >> 5;
  const int wg = blockIdx.x;
  const int sw = ((wg & 7) << 5) | (wg >> 3);
  const int bx = sw & 15, by = sw >> 4;
  const int m0 = by << 8, n0 = bx << 8;

  const int tid = threadIdx.x;
  const int w = tid >> 6, lane = tid & 63;
  const int wr = w >> 2, wc = w & 3;
  const int lr = lane & 15;
  const int phys = (lane >> 4) ^ ((lr >> 1) & 3);
  const int aoff = (wr * 128 + lr) * 32 + phys * 8;
  const int boff = 8192 + (wc * 64 + lr) * 32 + phys * 8;
  const int rst = w * 16 + (lane >> 2);
  const int ssrc = ((lane & 3) ^ ((lane >> 3) & 3)) * 8;

  f32x4 acc[8][4];
#pragma unroll
  for (int m = 0; m < 8; ++m)
#pragma unroll
    for (int n = 0; n < 4; ++n) acc[m][n] = {0.f, 0.f, 0.f, 0.f};

  const unsigned short* gA = A + (size_t)(m0 + rst) * K + ssrc;
  const unsigned short* gB = B + (size_t)(n0 + rst) * K + ssrc;
  const size_t jstep = (size_t)128 * K;

  // prologue: stage tiles 0..2 into slots 0..2
#pragma unroll
  for (int tau = 0; tau < 3; ++tau) {
    const int so = tau * 16384 + (w << 9);
    gload_lds16(gA + (size_t)tau * 32, &lds[so]);
    gload_lds16(gA + (size_t)tau * 32 + jstep, &lds[so + 4096]);
    gload_lds16(gB + (size_t)tau * 32, &lds[so + 8192]);
    gload_lds16(gB + (size_t)tau * 32 + jstep, &lds[so + 12288]);
  }
  asm volatile("s_waitcnt vmcnt(8)");
  SCHED; SBAR; SCHED;

  for (int t = 0; t < NT; ++t) {
    const int sb = (t & 3) * 16384;
    if (t + 3 < NT) {
      const int so = ((t + 3) & 3) * 16384 + (w << 9);
      const unsigned short* srcA = gA + (size_t)(t + 3) * 32;
      const unsigned short* srcB = gB + (size_t)(t + 3) * 32;
      gload_lds16(srcA, &lds[so]);
      gload_lds16(srcA + jstep, &lds[so + 4096]);
      gload_lds16(srcB, &lds[so + 8192]);
      gload_lds16(srcB + jstep, &lds[so + 12288]);
    }
    short8v bfr[4], af0[4], af1[4];
#pragma unroll
    for (int n = 0; n < 4; ++n)
      bfr[n] = *(const short8v*)&lds[sb + boff + n * 512];
#pragma unroll
    for (int m = 0; m < 4; ++m)
      af0[m] = *(const short8v*)&lds[sb + aoff + m * 512];
#pragma unroll
    for (int m = 0; m < 4; ++m)
      af1[m] = *(const short8v*)&lds[sb + aoff + 2048 + m * 512];
    __builtin_amdgcn_s_setprio(1);
#pragma unroll
    for (int m = 0; m < 4; ++m)
#pragma unroll
      for (int n = 0; n < 4; ++n)
        acc[m][n] = __builtin_amdgcn_mfma_f32_16x16x32_bf16(af0[m], bfr[n], acc[m][n], 0, 0, 0);
#pragma unroll
    for (int m = 0; m < 4; ++m)
#pragma unroll
      for (int n = 0; n < 4; ++n)
        acc[4 + m][n] = __builtin_amdgcn_mfma_f32_16x16x32_bf16(af1[m], bfr[n], acc[4 + m][n], 0, 0, 0);
    __builtin_amdgcn_s_setprio(0);
    SCHED;
    if (t < NT - 3)       { asm volatile("s_waitcnt vmcnt(8)"); }
    else if (t == NT - 3) { asm volatile("s_waitcnt vmcnt(4)"); }
    else if (t == NT - 2) { asm volatile("s_waitcnt vmcnt(0)"); }
    SCHED;
    if (t < NT - 1) { SBAR; SCHED; }
  }

  const int crow = m0 + wr * 128 + ((lane >> 4) << 2);
  const int ccol = n0 + wc * 64 + lr;
#pragma unroll
  for (int mi = 0; mi < 8; ++mi)
#pragma unroll
    for (int r = 0; r < 4; ++r) {
      const int row = crow + mi * 16 + r;
#pragma unroll
      for (int n = 0; n < 4; ++n) {
        const int col = ccol + n * 16;
        const float f = acc[mi][n][r];
        const size_t o = (size_t)row * N + col;
        if (EPI == 0) Cf[o] = f;
        else          Ch[o] = f2bf(f);
      }
    }
}

// ---------- row softmax: fp32 (n per row) -> bf16 p ----------
__global__ __launch_bounds__(256) void softmax_rows(
    const float* __restrict__ S, unsigned short* __restrict__ P, int n) {
  const int row = blockIdx.x;
  const int t = threadIdx.x;
  const float4* src = (const float4*)(S + (size_t)row * n);
  float4 v[4];
  float mx = -3.0e38f;
#pragma unroll
  for (int i = 0; i < 4; ++i) {
    v[i] = src[i * 256 + t];
    mx = fmaxf(mx, fmaxf(fmaxf(v[i].x, v[i].y), fmaxf(v[i].z, v[i].w)));
  }
#pragma unroll
  for (int off = 32; off; off >>= 1) mx = fmaxf(mx, __shfl_xor(mx, off));
  __shared__ float redm[4], reds[4];
  const int wid = t >> 6, lane = t & 63;
  if (lane == 0) redm[wid] = mx;
  __syncthreads();
  mx = fmaxf(fmaxf(redm[0], redm[1]), fmaxf(redm[2], redm[3]));
  float sum = 0.f;
#pragma unroll
  for (int i = 0; i < 4; ++i) {
    v[i].x = __expf(v[i].x - mx);
    v[i].y = __expf(v[i].y - mx);
    v[i].z = __expf(v[i].z - mx);
    v[i].w = __expf(v[i].w - mx);
    sum += (v[i].x + v[i].y) + (v[i].z + v[i].w);
  }
#pragma unroll
  for (int off = 32; off; off >>= 1) sum += __shfl_xor(sum, off);
  if (lane == 0) reds[wid] = sum;
  __syncthreads();
  sum = (reds[0] + reds[1]) + (reds[2] + reds[3]);
  float inv = 1.0f / sum;
#pragma unroll
  for (int i = 0; i < 4; ++i) {
    ushort4 o;
    o.x = f2bf(v[i].x * inv);
    o.y = f2bf(v[i].y * inv);
    o.z = f2bf(v[i].z * inv);
    o.w = f2bf(v[i].w * inv);
    *(ushort4*)(P + (size_t)row * n + (size_t)(i * 256 + t) * 4) = o;
  }
}

// ---------- launch ----------
extern "C" void kernel_launch(void* const* d_in, const int* in_sizes, int n_in,
                              void* d_out, int out_size, void* d_ws, size_t ws_size,
                              hipStream_t stream) {
  (void)in_sizes; (void)n_in; (void)out_size; (void)ws_size;
  const float* x  = (const float*)d_in[0];
  const float* Wq = (const float*)d_in[1];
  const float* Wk = (const float*)d_in[2];
  const float* Wv = (const float*)d_in[3];
  const int N = 4096, D = 1024;
  const size_t MB = 1ull << 20;
  char* ws = (char*)d_ws;
  unsigned short* xh  = (unsigned short*)(ws + 0 * MB);     // 8 MB
  unsigned short* xl  = (unsigned short*)(ws + 8 * MB);     // 8 MB
  unsigned short* wqh = (unsigned short*)(ws + 16 * MB);    // 8 MB
  unsigned short* wql = (unsigned short*)(ws + 24 * MB);    // 8 MB
  unsigned short* wkh = (unsigned short*)(ws + 32 * MB);    // 8 MB
  unsigned short* wkl = (unsigned short*)(ws + 40 * MB);    // 8 MB
  unsigned short* wvh = (unsigned short*)(ws + 48 * MB);    // 8 MB
  unsigned short* wvl = (unsigned short*)(ws + 56 * MB);    // 8 MB (written, unused)
  unsigned short* qh  = (unsigned short*)(ws + 64 * MB);    // 32 MB
  unsigned short* ql  = (unsigned short*)(ws + 96 * MB);    // 32 MB
  unsigned short* kh  = (unsigned short*)(ws + 128 * MB);   // 32 MB
  unsigned short* kl  = (unsigned short*)(ws + 160 * MB);   // 32 MB
  unsigned short* vT  = (unsigned short*)(ws + 16 * MB);    // 32 MB, over wq/wk splits (dead)
  unsigned short* p   = (unsigned short*)(ws + 64 * MB);    // 32 MB, over qh (dead)
  float* score = (float*)d_out;
  float* out   = (float*)d_out;

  // 1) splits
  split_plain<<<(N * D / 4 + 255) / 256, 256, 0, stream>>>(
      (const float4*)x, (ushort4*)xh, (ushort4*)xl, N * D / 4);
  dim3 gT(N / 32, D / 32);
  split_T<<<gT, 256, 0, stream>>>(Wq, wqh, wql, D, N);
  split_T<<<gT, 256, 0, stream>>>(Wk, wkh, wkl, D, N);
  split_T<<<gT, 256, 0, stream>>>(Wv, wvh, wvl, D, N);

  const int GG = (N / 256) * (N / 256);   // 256 workgroups
  // 2) q = x@Wq fused 3-product split -> hi/lo bf16
  gemm_fused3<2><<<GG, 512, 0, stream>>>(xh, xl, wqh, wql, N, D, nullptr, qh, ql);
  // 3) k = x@Wk
  gemm_fused3<2><<<GG, 512, 0, stream>>>(xh, xl, wkh, wkl, N, D, nullptr, kh, kl);
  // 4) vT = (x@Wv)^T  (plain bf16, 1-pass)
  gemm_plain<1><<<GG, 512, 0, stream>>>(wvh, xh, N, D, nullptr, vT);
  // 5) score = q@k^T fused, K=4096 -> fp32 d_out
  gemm_fused3<0><<<GG, 512, 0, stream>>>(qh, ql, kh, kl, N, N, score, nullptr, nullptr);
  // 6) p = softmax(score) -> bf16
  softmax_rows<<<N, 256, 0, stream>>>(score, p, N);
  // 7) out = p @ vT^T -> fp32 d_out
  gemm_plain<0><<<GG, 512, 0, stream>>>(p, vT, N, N, out, nullptr);
}

// Round 7
// 926.872 us; speedup vs baseline: 1.1340x; 1.1340x over previous
//
#include <hip/hip_runtime.h>
#include <hip/hip_bf16.h>
#include <stdint.h>

// ---------- helpers ----------
typedef __attribute__((ext_vector_type(8))) short short8v;   // 8 x bf16 bits (4 VGPRs)
typedef __attribute__((ext_vector_type(4))) float f32x4;

__device__ __forceinline__ unsigned short f2bf(float f) {
  unsigned u = __builtin_bit_cast(unsigned, f);
  unsigned r = 0x7fffu + ((u >> 16) & 1u);          // round-to-nearest-even
  return (unsigned short)((u + r) >> 16);
}
__device__ __forceinline__ float bf2f(unsigned short h) {
  unsigned u = ((unsigned)h) << 16;
  return __builtin_bit_cast(float, u);
}
__device__ __forceinline__ void gload_lds16(const void* g, void* l) {
  __builtin_amdgcn_global_load_lds(
      (const __attribute__((address_space(1))) void*)g,
      (__attribute__((address_space(3))) void*)l, 16, 0, 0);
}
#define SBAR  __builtin_amdgcn_s_barrier()
#define SCHED __builtin_amdgcn_sched_barrier(0)

// ---------- split kernels ----------
__global__ __launch_bounds__(256) void split_plain(
    const float4* __restrict__ X, ushort4* __restrict__ H, ushort4* __restrict__ L, int n4) {
  int idx = blockIdx.x * 256 + threadIdx.x;
  if (idx >= n4) return;
  float4 v = X[idx];
  ushort4 h, l;
  h.x = f2bf(v.x); l.x = f2bf(v.x - bf2f(h.x));
  h.y = f2bf(v.y); l.y = f2bf(v.y - bf2f(h.y));
  h.z = f2bf(v.z); l.z = f2bf(v.z - bf2f(h.z));
  h.w = f2bf(v.w); l.w = f2bf(v.w - bf2f(h.w));
  H[idx] = h; L[idx] = l;
}

__global__ __launch_bounds__(256) void split_T(
    const float* __restrict__ W, unsigned short* __restrict__ H,
    unsigned short* __restrict__ L, int Kd, int Nd) {
  __shared__ float tile[32][33];
  const int t = threadIdx.x;
  const int c = t & 31;
  const int r0 = t >> 5;
  const int k0 = blockIdx.y * 32, n0 = blockIdx.x * 32;
#pragma unroll
  for (int i = 0; i < 4; ++i) {
    int r = r0 + i * 8;
    tile[r][c] = W[(size_t)(k0 + r) * Nd + n0 + c];
  }
  __syncthreads();
#pragma unroll
  for (int i = 0; i < 4; ++i) {
    int n = r0 + i * 8;
    float f = tile[c][n];
    unsigned short h = f2bf(f);
    unsigned short l = f2bf(f - bf2f(h));
    size_t o = (size_t)(n0 + n) * Kd + k0 + c;
    H[o] = h; L[o] = l;
  }
}

// ---------- FUSED split GEMM: C = Ah@Bl^T + Ah@Bh^T + Al@Bh^T ----------
// 256x256 tile, BK=32, 2-slot ring. Sync skeleton = round-6 (tripwire-proven):
// every sub-block {vmcnt(N); SBAR; reads; stage(t+1); MFMA}. Spill fix vs r6:
// (a) launch_bounds(512,1) — LDS caps CU at 1 wg anyway, lift the 256-reg cap;
// (b) product order (h,l),(h,h),(l,h) with stage FIFO [Ah,Bl,Bh,Al] so peak
//     live frags = 48 regs (ahf blocks 1-2, bhf 2-3, blf/alf single-block).
// vmcnt never 0 mid-loop. EPI 0: fp32 C; 2: split hi/lo bf16.
template<int EPI>
__global__ __launch_bounds__(512, 1) void gemm_fused3(
    const unsigned short* __restrict__ Ah_, const unsigned short* __restrict__ Al_,
    const unsigned short* __restrict__ Bh_, const unsigned short* __restrict__ Bl_,
    int N, int K,
    float* __restrict__ Cf, unsigned short* __restrict__ Ch, unsigned short* __restrict__ Cl) {
  // 2 slots x [Ah|Bh|Bl|Al] x 8192 ush = 65536 ush = 128 KiB
  __shared__ unsigned short lds[65536];
  const int AH = 0, BH = 8192, BL = 16384, AL = 24576;
  const int NT = K >> 5;
  const int wg = blockIdx.x;
  const int sw = ((wg & 7) << 5) | (wg >> 3);     // XCD-bijective (256 wg)
  const int bx = sw & 15, by = sw >> 4;
  const int m0 = by << 8, n0 = bx << 8;

  const int tid = threadIdx.x;
  const int w = tid >> 6, lane = tid & 63;
  const int wr = w >> 2, wc = w & 3;               // wave tile 128x64
  const int lr = lane & 15;
  // read-side swizzle: phys 16B-slot = logical ^ ((row>>1)&3)
  const int phys = (lane >> 4) ^ ((lr >> 1) & 3);
  const int aoff = (wr * 128 + lr) * 32 + phys * 8;   // + m*512
  const int boff = (wc * 64 + lr) * 32 + phys * 8;    // + n*512
  // stage-side: linear LDS dest, inverse-swizzled global source (Rule 21)
  const int rst = tid >> 2;                            // source row 0..127
  const int ssrc = ((tid & 3) ^ ((tid >> 3) & 3)) * 8; // source k-slot (elements)
  const size_t jstep = (size_t)128 * K;

  const unsigned short* gAh = Ah_ + (size_t)(m0 + rst) * K + ssrc;
  const unsigned short* gAl = Al_ + (size_t)(m0 + rst) * K + ssrc;
  const unsigned short* gBh = Bh_ + (size_t)(n0 + rst) * K + ssrc;
  const unsigned short* gBl = Bl_ + (size_t)(n0 + rst) * K + ssrc;

  f32x4 acc[8][4];
#pragma unroll
  for (int m = 0; m < 8; ++m)
#pragma unroll
    for (int n = 0; n < 4; ++n) acc[m][n] = {0.f, 0.f, 0.f, 0.f};

#define STG2(gp, off, slot1, tt) do {                                   \
    const unsigned short* s_ = (gp) + (size_t)(tt) * 32;                \
    gload_lds16(s_, &lds[(slot1) + (off) + (w << 9)]);                  \
    gload_lds16(s_ + jstep, &lds[(slot1) + (off) + 4096 + (w << 9)]);   \
  } while (0)

  // prologue: stage tile 0 into slot 0, FIFO order [Ah, Bl, Bh, Al]  (8 ops)
  STG2(gAh, AH, 0, 0);
  STG2(gBl, BL, 0, 0);
  STG2(gBh, BH, 0, 0);
  STG2(gAl, AL, 0, 0);

  for (int t = 0; t < NT; ++t) {
    const int slot = (t & 1) << 15;         // *32768
    const int slot1 = ((t + 1) & 1) << 15;
    const bool st = (t + 1) < NT;
    // ---- block1 (h,l): certify Ah(t),Bl(t); outstanding 8 -> vmcnt(4) ----
    {
      SCHED; asm volatile("s_waitcnt vmcnt(4)"); SBAR; SCHED;
      short8v blf[4];
      short8v ahf[8];
#pragma unroll
      for (int n = 0; n < 4; ++n)
        blf[n] = *(const short8v*)&lds[slot + BL + boff + n * 512];
#pragma unroll
      for (int m = 0; m < 8; ++m)
        ahf[m] = *(const short8v*)&lds[slot + AH + aoff + m * 512];
      if (st) { STG2(gAh, AH, slot1, t + 1); STG2(gBl, BL, slot1, t + 1); }
      __builtin_amdgcn_s_setprio(1);
#pragma unroll
      for (int m = 0; m < 8; ++m)
#pragma unroll
        for (int n = 0; n < 4; ++n)
          acc[m][n] = __builtin_amdgcn_mfma_f32_16x16x32_bf16(ahf[m], blf[n], acc[m][n], 0, 0, 0);
      __builtin_amdgcn_s_setprio(0);
      // ---- block2 (h,h): certify Bh(t); outstanding [Bh,Al,Ah',Bl']=8 -> vmcnt(6) ----
      SCHED;
      if (st) { asm volatile("s_waitcnt vmcnt(6)"); }
      else    { asm volatile("s_waitcnt vmcnt(2)"); }   // [Bh,Al] -> Bh done
      SBAR; SCHED;
      short8v bhf[4];
#pragma unroll
      for (int n = 0; n < 4; ++n)
        bhf[n] = *(const short8v*)&lds[slot + BH + boff + n * 512];
      if (st) { STG2(gBh, BH, slot1, t + 1); }
      __builtin_amdgcn_s_setprio(1);
#pragma unroll
      for (int m = 0; m < 8; ++m)
#pragma unroll
        for (int n = 0; n < 4; ++n)
          acc[m][n] = __builtin_amdgcn_mfma_f32_16x16x32_bf16(ahf[m], bhf[n], acc[m][n], 0, 0, 0);
      __builtin_amdgcn_s_setprio(0);
      // ahf dies here (scope trick keeps liveness explicit)
      // ---- block3 (l,h): certify Al(t); outstanding [Al,Ah',Bl',Bh']=8 -> vmcnt(6) ----
      SCHED;
      if (st) { asm volatile("s_waitcnt vmcnt(6)"); }
      else    { asm volatile("s_waitcnt vmcnt(0)"); }   // [Al] -> done
      SBAR; SCHED;
      short8v alf[8];
#pragma unroll
      for (int m = 0; m < 8; ++m)
        alf[m] = *(const short8v*)&lds[slot + AL + aoff + m * 512];
      if (st) { STG2(gAl, AL, slot1, t + 1); }
      __builtin_amdgcn_s_setprio(1);
#pragma unroll
      for (int m = 0; m < 8; ++m)
#pragma unroll
        for (int n = 0; n < 4; ++n)
          acc[m][n] = __builtin_amdgcn_mfma_f32_16x16x32_bf16(alf[m], bhf[n], acc[m][n], 0, 0, 0);
      __builtin_amdgcn_s_setprio(0);
      SCHED;
    }
    // no end-of-tile barrier: block1's SBAR of tile t+1 separates the last
    // reads of slot (t-1)&1 from the next writes to it.
  }
#undef STG2

  // epilogue: frag r -> row=(lane>>4)*4+r, col=lane&15  [m89/m91-verified]
  const int crow = m0 + wr * 128 + ((lane >> 4) << 2);
  const int ccol = n0 + wc * 64 + lr;
#pragma unroll
  for (int mi = 0; mi < 8; ++mi)
#pragma unroll
    for (int r = 0; r < 4; ++r) {
      const int row = crow + mi * 16 + r;
#pragma unroll
      for (int n = 0; n < 4; ++n) {
        const int col = ccol + n * 16;
        const float f = acc[mi][n][r];
        const size_t o = (size_t)row * N + col;
        if (EPI == 0) {
          Cf[o] = f;
        } else {
          const unsigned short h = f2bf(f);
          Ch[o] = h;
          Cl[o] = f2bf(f - bf2f(h));
        }
      }
    }
}

// ---------- plain single-pass GEMM (round-2 proven): C = A @ B^T ----------
// 4-deep ring, counted vmcnt 8/4/0 BEFORE the barrier, one SBAR per tile.
// EPI 0: fp32; 1: bf16.
template<int EPI>
__global__ __launch_bounds__(512, 2) void gemm_plain(
    const unsigned short* __restrict__ A, const unsigned short* __restrict__ B,
    int N, int K,
    float* __restrict__ Cf, unsigned short* __restrict__ Ch) {
  __shared__ unsigned short lds[65536];   // 4 slots x (A 8192 + B 8192)
  const int NT = K >> 5;
  const int wg = blockIdx.x;
  const int sw = ((wg & 7) << 5) | (wg >> 3);
  const int bx = sw & 15, by = sw >> 4;
  const int m0 = by << 8, n0 = bx << 8;

  const int tid = threadIdx.x;
  const int w = tid >> 6, lane = tid & 63;
  const int wr = w >> 2, wc = w & 3;
  const int lr = lane & 15;
  const int phys = (lane >> 4) ^ ((lr >> 1) & 3);
  const int aoff = (wr * 128 + lr) * 32 + phys * 8;
  const int boff = 8192 + (wc * 64 + lr) * 32 + phys * 8;
  const int rst = w * 16 + (lane >> 2);
  const int ssrc = ((lane & 3) ^ ((lane >> 3) & 3)) * 8;

  f32x4 acc[8][4];
#pragma unroll
  for (int m = 0; m < 8; ++m)
#pragma unroll
    for (int n = 0; n < 4; ++n) acc[m][n] = {0.f, 0.f, 0.f, 0.f};

  const unsigned short* gA = A + (size_t)(m0 + rst) * K + ssrc;
  const unsigned short* gB = B + (size_t)(n0 + rst) * K + ssrc;
  const size_t jstep = (size_t)128 * K;

  // prologue: stage tiles 0..2 into slots 0..2
#pragma unroll
  for (int tau = 0; tau < 3; ++tau) {
    const int so = tau * 16384 + (w << 9);
    gload_lds16(gA + (size_t)tau * 32, &lds[so]);
    gload_lds16(gA + (size_t)tau * 32 + jstep, &lds[so + 4096]);
    gload_lds16(gB + (size_t)tau * 32, &lds[so + 8192]);
    gload_lds16(gB + (size_t)tau * 32 + jstep, &lds[so + 12288]);
  }
  asm volatile("s_waitcnt vmcnt(8)");
  SCHED; SBAR; SCHED;

  for (int t = 0; t < NT; ++t) {
    const int sb = (t & 3) * 16384;
    if (t + 3 < NT) {
      const int so = ((t + 3) & 3) * 16384 + (w << 9);
      const unsigned short* srcA = gA + (size_t)(t + 3) * 32;
      const unsigned short* srcB = gB + (size_t)(t + 3) * 32;
      gload_lds16(srcA, &lds[so]);
      gload_lds16(srcA + jstep, &lds[so + 4096]);
      gload_lds16(srcB, &lds[so + 8192]);
      gload_lds16(srcB + jstep, &lds[so + 12288]);
    }
    short8v bfr[4], af0[4], af1[4];
#pragma unroll
    for (int n = 0; n < 4; ++n)
      bfr[n] = *(const short8v*)&lds[sb + boff + n * 512];
#pragma unroll
    for (int m = 0; m < 4; ++m)
      af0[m] = *(const short8v*)&lds[sb + aoff + m * 512];
#pragma unroll
    for (int m = 0; m < 4; ++m)
      af1[m] = *(const short8v*)&lds[sb + aoff + 2048 + m * 512];
    __builtin_amdgcn_s_setprio(1);
#pragma unroll
    for (int m = 0; m < 4; ++m)
#pragma unroll
      for (int n = 0; n < 4; ++n)
        acc[m][n] = __builtin_amdgcn_mfma_f32_16x16x32_bf16(af0[m], bfr[n], acc[m][n], 0, 0, 0);
#pragma unroll
    for (int m = 0; m < 4; ++m)
#pragma unroll
      for (int n = 0; n < 4; ++n)
        acc[4 + m][n] = __builtin_amdgcn_mfma_f32_16x16x32_bf16(af1[m], bfr[n], acc[4 + m][n], 0, 0, 0);
    __builtin_amdgcn_s_setprio(0);
    SCHED;
    if (t < NT - 3)       { asm volatile("s_waitcnt vmcnt(8)"); }
    else if (t == NT - 3) { asm volatile("s_waitcnt vmcnt(4)"); }
    else if (t == NT - 2) { asm volatile("s_waitcnt vmcnt(0)"); }
    SCHED;
    if (t < NT - 1) { SBAR; SCHED; }
  }

  const int crow = m0 + wr * 128 + ((lane >> 4) << 2);
  const int ccol = n0 + wc * 64 + lr;
#pragma unroll
  for (int mi = 0; mi < 8; ++mi)
#pragma unroll
    for (int r = 0; r < 4; ++r) {
      const int row = crow + mi * 16 + r;
#pragma unroll
      for (int n = 0; n < 4; ++n) {
        const int col = ccol + n * 16;
        const float f = acc[mi][n][r];
        const size_t o = (size_t)row * N + col;
        if (EPI == 0) Cf[o] = f;
        else          Ch[o] = f2bf(f);
      }
    }
}

// ---------- row softmax: fp32 (n per row) -> bf16 p ----------
__global__ __launch_bounds__(256) void softmax_rows(
    const float* __restrict__ S, unsigned short* __restrict__ P, int n) {
  const int row = blockIdx.x;
  const int t = threadIdx.x;
  const float4* src = (const float4*)(S + (size_t)row * n);
  float4 v[4];
  float mx = -3.0e38f;
#pragma unroll
  for (int i = 0; i < 4; ++i) {
    v[i] = src[i * 256 + t];
    mx = fmaxf(mx, fmaxf(fmaxf(v[i].x, v[i].y), fmaxf(v[i].z, v[i].w)));
  }
#pragma unroll
  for (int off = 32; off; off >>= 1) mx = fmaxf(mx, __shfl_xor(mx, off));
  __shared__ float redm[4], reds[4];
  const int wid = t >> 6, lane = t & 63;
  if (lane == 0) redm[wid] = mx;
  __syncthreads();
  mx = fmaxf(fmaxf(redm[0], redm[1]), fmaxf(redm[2], redm[3]));
  float sum = 0.f;
#pragma unroll
  for (int i = 0; i < 4; ++i) {
    v[i].x = __expf(v[i].x - mx);
    v[i].y = __expf(v[i].y - mx);
    v[i].z = __expf(v[i].z - mx);
    v[i].w = __expf(v[i].w - mx);
    sum += (v[i].x + v[i].y) + (v[i].z + v[i].w);
  }
#pragma unroll
  for (int off = 32; off; off >>= 1) sum += __shfl_xor(sum, off);
  if (lane == 0) reds[wid] = sum;
  __syncthreads();
  sum = (reds[0] + reds[1]) + (reds[2] + reds[3]);
  float inv = 1.0f / sum;
#pragma unroll
  for (int i = 0; i < 4; ++i) {
    ushort4 o;
    o.x = f2bf(v[i].x * inv);
    o.y = f2bf(v[i].y * inv);
    o.z = f2bf(v[i].z * inv);
    o.w = f2bf(v[i].w * inv);
    *(ushort4*)(P + (size_t)row * n + (size_t)(i * 256 + t) * 4) = o;
  }
}

// ---------- launch ----------
extern "C" void kernel_launch(void* const* d_in, const int* in_sizes, int n_in,
                              void* d_out, int out_size, void* d_ws, size_t ws_size,
                              hipStream_t stream) {
  (void)in_sizes; (void)n_in; (void)out_size; (void)ws_size;
  const float* x  = (const float*)d_in[0];
  const float* Wq = (const float*)d_in[1];
  const float* Wk = (const float*)d_in[2];
  const float* Wv = (const float*)d_in[3];
  const int N = 4096, D = 1024;
  const size_t MB = 1ull << 20;
  char* ws = (char*)d_ws;
  unsigned short* xh  = (unsigned short*)(ws + 0 * MB);     // 8 MB
  unsigned short* xl  = (unsigned short*)(ws + 8 * MB);     // 8 MB
  unsigned short* wqh = (unsigned short*)(ws + 16 * MB);    // 8 MB
  unsigned short* wql = (unsigned short*)(ws + 24 * MB);    // 8 MB
  unsigned short* wkh = (unsigned short*)(ws + 32 * MB);    // 8 MB
  unsigned short* wkl = (unsigned short*)(ws + 40 * MB);    // 8 MB
  unsigned short* wvh = (unsigned short*)(ws + 48 * MB);    // 8 MB
  unsigned short* wvl = (unsigned short*)(ws + 56 * MB);    // 8 MB (written, unused)
  unsigned short* qh  = (unsigned short*)(ws + 64 * MB);    // 32 MB
  unsigned short* ql  = (unsigned short*)(ws + 96 * MB);    // 32 MB
  unsigned short* kh  = (unsigned short*)(ws + 128 * MB);   // 32 MB
  unsigned short* kl  = (unsigned short*)(ws + 160 * MB);   // 32 MB
  unsigned short* vT  = (unsigned short*)(ws + 16 * MB);    // 32 MB, over wq/wk splits (dead)
  unsigned short* p   = (unsigned short*)(ws + 64 * MB);    // 32 MB, over qh (dead)
  float* score = (float*)d_out;
  float* out   = (float*)d_out;

  // 1) splits
  split_plain<<<(N * D / 4 + 255) / 256, 256, 0, stream>>>(
      (const float4*)x, (ushort4*)xh, (ushort4*)xl, N * D / 4);
  dim3 gT(N / 32, D / 32);
  split_T<<<gT, 256, 0, stream>>>(Wq, wqh, wql, D, N);
  split_T<<<gT, 256, 0, stream>>>(Wk, wkh, wkl, D, N);
  split_T<<<gT, 256, 0, stream>>>(Wv, wvh, wvl, D, N);

  const int GG = (N / 256) * (N / 256);   // 256 workgroups
  // 2) q = x@Wq fused 3-product split -> hi/lo bf16
  gemm_fused3<2><<<GG, 512, 0, stream>>>(xh, xl, wqh, wql, N, D, nullptr, qh, ql);
  // 3) k = x@Wk
  gemm_fused3<2><<<GG, 512, 0, stream>>>(xh, xl, wkh, wkl, N, D, nullptr, kh, kl);
  // 4) vT = (x@Wv)^T  (plain bf16, 1-pass)
  gemm_plain<1><<<GG, 512, 0, stream>>>(wvh, xh, N, D, nullptr, vT);
  // 5) score = q@k^T fused, K=4096 -> fp32 d_out
  gemm_fused3<0><<<GG, 512, 0, stream>>>(qh, ql, kh, kl, N, N, score, nullptr, nullptr);
  // 6) p = softmax(score) -> bf16
  softmax_rows<<<N, 256, 0, stream>>>(score, p, N);
  // 7) out = p @ vT^T -> fp32 d_out
  gemm_plain<0><<<GG, 512, 0, stream>>>(p, vT, N, N, out, nullptr);
}

// Round 8
// 690.292 us; speedup vs baseline: 1.5227x; 1.3427x over previous
//
#include <hip/hip_runtime.h>
#include <hip/hip_bf16.h>
#include <stdint.h>

// ---------- helpers ----------
typedef __attribute__((ext_vector_type(8))) short short8v;   // 8 x bf16 bits (4 VGPRs)
typedef __attribute__((ext_vector_type(4))) float f32x4;

__device__ __forceinline__ unsigned short f2bf(float f) {
  unsigned u = __builtin_bit_cast(unsigned, f);
  unsigned r = 0x7fffu + ((u >> 16) & 1u);          // round-to-nearest-even
  return (unsigned short)((u + r) >> 16);
}
__device__ __forceinline__ float bf2f(unsigned short h) {
  unsigned u = ((unsigned)h) << 16;
  return __builtin_bit_cast(float, u);
}
__device__ __forceinline__ void gload_lds16(const void* g, void* l) {
  __builtin_amdgcn_global_load_lds(
      (const __attribute__((address_space(1))) void*)g,
      (__attribute__((address_space(3))) void*)l, 16, 0, 0);
}
#define SBAR  __builtin_amdgcn_s_barrier()
#define SCHED __builtin_amdgcn_sched_barrier(0)

// ---------- split kernels ----------
__global__ __launch_bounds__(256) void split_plain(
    const float4* __restrict__ X, ushort4* __restrict__ H, ushort4* __restrict__ L, int n4) {
  int idx = blockIdx.x * 256 + threadIdx.x;
  if (idx >= n4) return;
  float4 v = X[idx];
  ushort4 h, l;
  h.x = f2bf(v.x); l.x = f2bf(v.x - bf2f(h.x));
  h.y = f2bf(v.y); l.y = f2bf(v.y - bf2f(h.y));
  h.z = f2bf(v.z); l.z = f2bf(v.z - bf2f(h.z));
  h.w = f2bf(v.w); l.w = f2bf(v.w - bf2f(h.w));
  H[idx] = h; L[idx] = l;
}

__global__ __launch_bounds__(256) void split_T(
    const float* __restrict__ W, unsigned short* __restrict__ H,
    unsigned short* __restrict__ L, int Kd, int Nd) {
  __shared__ float tile[32][33];
  const int t = threadIdx.x;
  const int c = t & 31;
  const int r0 = t >> 5;
  const int k0 = blockIdx.y * 32, n0 = blockIdx.x * 32;
#pragma unroll
  for (int i = 0; i < 4; ++i) {
    int r = r0 + i * 8;
    tile[r][c] = W[(size_t)(k0 + r) * Nd + n0 + c];
  }
  __syncthreads();
#pragma unroll
  for (int i = 0; i < 4; ++i) {
    int n = r0 + i * 8;
    float f = tile[c][n];
    unsigned short h = f2bf(f);
    unsigned short l = f2bf(f - bf2f(h));
    size_t o = (size_t)(n0 + n) * Kd + k0 + c;
    H[o] = h; L[o] = l;
  }
}

// ---------- FUSED split GEMM: C = Ah@Bl^T + Ah@Bh^T + Al@Bh^T ----------
// All operands addressed from ONE base pointer + uniform element offsets
// (SGPR base + 32-bit per-lane offset -> minimal address VGPRs).
// 256x256 tile, BK=32, 2-slot ring. Sync skeleton = r6/r7 (tripwire-proven):
// each sub-block {vmcnt(N); SBAR; reads; stage(t+1); MFMA}; stage FIFO
// [Ah,Bl,Bh,Al]; vmcnt 4/6/6 steady, 4/2/0 tail. A-frags read 4-at-a-time
// and re-read per product block (m-split) to cap frag liveness.
// EPI 0: fp32 C; 2: split hi/lo bf16.
template<int EPI>
__global__ __launch_bounds__(512, 1) void gemm_fused3(
    const unsigned short* __restrict__ base,            // = Ah
    unsigned dAl, unsigned dBh, unsigned dBl,           // element offsets
    int N, int K,
    float* __restrict__ Cf, unsigned short* __restrict__ Ch, unsigned short* __restrict__ Cl) {
  // 2 slots x [Ah|Bh|Bl|Al] x 8192 ush = 65536 ush = 128 KiB
  __shared__ unsigned short lds[65536];
  const int AH = 0, BH = 8192, BL = 16384, AL = 24576;
  const int NT = K >> 5;
  const int wg = blockIdx.x;
  const int sw = ((wg & 7) << 5) | (wg >> 3);     // XCD-bijective (256 wg)
  const int bx = sw & 15, by = sw >> 4;
  const int m0 = by << 8, n0 = bx << 8;

  const int tid = threadIdx.x;
  const int w = tid >> 6, lane = tid & 63;
  const int wr = w >> 2, wc = w & 3;               // wave tile 128x64
  const int lr = lane & 15;
  // read-side swizzle: phys 16B-slot = logical ^ ((row>>1)&3)
  const int phys = (lane >> 4) ^ ((lr >> 1) & 3);
  const int aoff = (wr * 128 + lr) * 32 + phys * 8;   // + m*512 (+2048 m>=4)
  const int boff = (wc * 64 + lr) * 32 + phys * 8;    // + n*512
  // stage-side: linear LDS dest, inverse-swizzled global source (Rule 21)
  const int rst = tid >> 2;                            // source row 0..127
  const int ssrc = ((tid & 3) ^ ((tid >> 3) & 3)) * 8; // source k-slot (elements)
  const unsigned jstep = 128u * (unsigned)K;

  const unsigned voffA = (unsigned)(m0 + rst) * (unsigned)K + (unsigned)ssrc;
  const unsigned voffB = (unsigned)(n0 + rst) * (unsigned)K + (unsigned)ssrc;

  f32x4 acc[8][4];
#pragma unroll
  for (int m = 0; m < 8; ++m)
#pragma unroll
    for (int n = 0; n < 4; ++n) acc[m][n] = {0.f, 0.f, 0.f, 0.f};

  // stage one operand subtile (2 gload ops) into slot s for K-tile tt
#define STG2(dsel, vo, loff, s, tt) do {                                     \
    const unsigned o_ = (vo) + (dsel) + (unsigned)(tt) * 32u;                \
    gload_lds16(base + o_,         &lds[(s) + (loff) + (w << 9)]);           \
    gload_lds16(base + o_ + jstep, &lds[(s) + (loff) + 4096 + (w << 9)]);    \
  } while (0)

  // prologue: stage tile 0 into slot 0, FIFO order [Ah, Bl, Bh, Al]  (8 ops)
  STG2(0u,  voffA, AH, 0, 0);
  STG2(dBl, voffB, BL, 0, 0);
  STG2(dBh, voffB, BH, 0, 0);
  STG2(dAl, voffA, AL, 0, 0);

  for (int t = 0; t < NT; ++t) {
    const int slot = (t & 1) << 15;         // *32768
    const int slot1 = ((t + 1) & 1) << 15;
    const bool st = (t + 1) < NT;
    // ---- block1 (h,l): certify Ah(t),Bl(t); outstanding 8 -> vmcnt(4) ----
    SCHED; asm volatile("s_waitcnt vmcnt(4)"); SBAR; SCHED;
    {
      short8v bf[4], af[4], af2[4];
#pragma unroll
      for (int n = 0; n < 4; ++n)
        bf[n] = *(const short8v*)&lds[slot + BL + boff + n * 512];
#pragma unroll
      for (int m = 0; m < 4; ++m)
        af[m] = *(const short8v*)&lds[slot + AH + aoff + m * 512];
      if (st) { STG2(0u, voffA, AH, slot1, t + 1); STG2(dBl, voffB, BL, slot1, t + 1); }
      __builtin_amdgcn_s_setprio(1);
#pragma unroll
      for (int m = 0; m < 4; ++m)
#pragma unroll
        for (int n = 0; n < 4; ++n)
          acc[m][n] = __builtin_amdgcn_mfma_f32_16x16x32_bf16(af[m], bf[n], acc[m][n], 0, 0, 0);
      __builtin_amdgcn_s_setprio(0);
#pragma unroll
      for (int m = 0; m < 4; ++m)
        af2[m] = *(const short8v*)&lds[slot + AH + aoff + 2048 + m * 512];
      __builtin_amdgcn_s_setprio(1);
#pragma unroll
      for (int m = 0; m < 4; ++m)
#pragma unroll
        for (int n = 0; n < 4; ++n)
          acc[4 + m][n] = __builtin_amdgcn_mfma_f32_16x16x32_bf16(af2[m], bf[n], acc[4 + m][n], 0, 0, 0);
      __builtin_amdgcn_s_setprio(0);
    }
    // ---- block2 (h,h): certify Bh(t); vmcnt(6) steady / (2) tail ----
    SCHED;
    if (st) { asm volatile("s_waitcnt vmcnt(6)"); }
    else    { asm volatile("s_waitcnt vmcnt(2)"); }
    SBAR; SCHED;
    short8v bh[4];                      // lives through block3
    {
      short8v af[4], af2[4];
#pragma unroll
      for (int n = 0; n < 4; ++n)
        bh[n] = *(const short8v*)&lds[slot + BH + boff + n * 512];
#pragma unroll
      for (int m = 0; m < 4; ++m)
        af[m] = *(const short8v*)&lds[slot + AH + aoff + m * 512];
      if (st) { STG2(dBh, voffB, BH, slot1, t + 1); }
      __builtin_amdgcn_s_setprio(1);
#pragma unroll
      for (int m = 0; m < 4; ++m)
#pragma unroll
        for (int n = 0; n < 4; ++n)
          acc[m][n] = __builtin_amdgcn_mfma_f32_16x16x32_bf16(af[m], bh[n], acc[m][n], 0, 0, 0);
      __builtin_amdgcn_s_setprio(0);
#pragma unroll
      for (int m = 0; m < 4; ++m)
        af2[m] = *(const short8v*)&lds[slot + AH + aoff + 2048 + m * 512];
      __builtin_amdgcn_s_setprio(1);
#pragma unroll
      for (int m = 0; m < 4; ++m)
#pragma unroll
        for (int n = 0; n < 4; ++n)
          acc[4 + m][n] = __builtin_amdgcn_mfma_f32_16x16x32_bf16(af2[m], bh[n], acc[4 + m][n], 0, 0, 0);
      __builtin_amdgcn_s_setprio(0);
    }
    // ---- block3 (l,h): certify Al(t); vmcnt(6) steady / (0) tail ----
    SCHED;
    if (st) { asm volatile("s_waitcnt vmcnt(6)"); }
    else    { asm volatile("s_waitcnt vmcnt(0)"); }
    SBAR; SCHED;
    {
      short8v af[4], af2[4];
#pragma unroll
      for (int m = 0; m < 4; ++m)
        af[m] = *(const short8v*)&lds[slot + AL + aoff + m * 512];
      if (st) { STG2(dAl, voffA, AL, slot1, t + 1); }
      __builtin_amdgcn_s_setprio(1);
#pragma unroll
      for (int m = 0; m < 4; ++m)
#pragma unroll
        for (int n = 0; n < 4; ++n)
          acc[m][n] = __builtin_amdgcn_mfma_f32_16x16x32_bf16(af[m], bh[n], acc[m][n], 0, 0, 0);
      __builtin_amdgcn_s_setprio(0);
#pragma unroll
      for (int m = 0; m < 4; ++m)
        af2[m] = *(const short8v*)&lds[slot + AL + aoff + 2048 + m * 512];
      __builtin_amdgcn_s_setprio(1);
#pragma unroll
      for (int m = 0; m < 4; ++m)
#pragma unroll
        for (int n = 0; n < 4; ++n)
          acc[4 + m][n] = __builtin_amdgcn_mfma_f32_16x16x32_bf16(af2[m], bh[n], acc[4 + m][n], 0, 0, 0);
      __builtin_amdgcn_s_setprio(0);
    }
    SCHED;
    // no end-of-tile barrier: block1's SBAR of tile t+1 separates the last
    // reads of slot (t-1)&1 from the next writes to it.
  }
#undef STG2

  // epilogue: frag r -> row=(lane>>4)*4+r, col=lane&15  [m89/m91-verified]
  const int crow = m0 + wr * 128 + ((lane >> 4) << 2);
  const int ccol = n0 + wc * 64 + lr;
#pragma unroll
  for (int mi = 0; mi < 8; ++mi)
#pragma unroll
    for (int r = 0; r < 4; ++r) {
      const int row = crow + mi * 16 + r;
#pragma unroll
      for (int n = 0; n < 4; ++n) {
        const int col = ccol + n * 16;
        const float f = acc[mi][n][r];
        const size_t o = (size_t)row * N + col;
        if (EPI == 0) {
          Cf[o] = f;
        } else {
          const unsigned short h = f2bf(f);
          Ch[o] = h;
          Cl[o] = f2bf(f - bf2f(h));
        }
      }
    }
}

// ---------- plain single-pass GEMM (round-2 proven): C = A @ B^T ----------
// 4-deep ring, counted vmcnt 8/4/0 BEFORE the barrier, one SBAR per tile.
// EPI 0: fp32; 1: bf16.
template<int EPI>
__global__ __launch_bounds__(512, 2) void gemm_plain(
    const unsigned short* __restrict__ A, const unsigned short* __restrict__ B,
    int N, int K,
    float* __restrict__ Cf, unsigned short* __restrict__ Ch) {
  __shared__ unsigned short lds[65536];   // 4 slots x (A 8192 + B 8192)
  const int NT = K >> 5;
  const int wg = blockIdx.x;
  const int sw = ((wg & 7) << 5) | (wg >> 3);
  const int bx = sw & 15, by = sw >> 4;
  const int m0 = by << 8, n0 = bx << 8;

  const int tid = threadIdx.x;
  const int w = tid >> 6, lane = tid & 63;
  const int wr = w >> 2, wc = w & 3;
  const int lr = lane & 15;
  const int phys = (lane >> 4) ^ ((lr >> 1) & 3);
  const int aoff = (wr * 128 + lr) * 32 + phys * 8;
  const int boff = 8192 + (wc * 64 + lr) * 32 + phys * 8;
  const int rst = w * 16 + (lane >> 2);
  const int ssrc = ((lane & 3) ^ ((lane >> 3) & 3)) * 8;

  f32x4 acc[8][4];
#pragma unroll
  for (int m = 0; m < 8; ++m)
#pragma unroll
    for (int n = 0; n < 4; ++n) acc[m][n] = {0.f, 0.f, 0.f, 0.f};

  const unsigned short* gA = A + (size_t)(m0 + rst) * K + ssrc;
  const unsigned short* gB = B + (size_t)(n0 + rst) * K + ssrc;
  const size_t jstep = (size_t)128 * K;

  // prologue: stage tiles 0..2 into slots 0..2
#pragma unroll
  for (int tau = 0; tau < 3; ++tau) {
    const int so = tau * 16384 + (w << 9);
    gload_lds16(gA + (size_t)tau * 32, &lds[so]);
    gload_lds16(gA + (size_t)tau * 32 + jstep, &lds[so + 4096]);
    gload_lds16(gB + (size_t)tau * 32, &lds[so + 8192]);
    gload_lds16(gB + (size_t)tau * 32 + jstep, &lds[so + 12288]);
  }
  asm volatile("s_waitcnt vmcnt(8)");
  SCHED; SBAR; SCHED;

  for (int t = 0; t < NT; ++t) {
    const int sb = (t & 3) * 16384;
    if (t + 3 < NT) {
      const int so = ((t + 3) & 3) * 16384 + (w << 9);
      const unsigned short* srcA = gA + (size_t)(t + 3) * 32;
      const unsigned short* srcB = gB + (size_t)(t + 3) * 32;
      gload_lds16(srcA, &lds[so]);
      gload_lds16(srcA + jstep, &lds[so + 4096]);
      gload_lds16(srcB, &lds[so + 8192]);
      gload_lds16(srcB + jstep, &lds[so + 12288]);
    }
    short8v bfr[4], af0[4], af1[4];
#pragma unroll
    for (int n = 0; n < 4; ++n)
      bfr[n] = *(const short8v*)&lds[sb + boff + n * 512];
#pragma unroll
    for (int m = 0; m < 4; ++m)
      af0[m] = *(const short8v*)&lds[sb + aoff + m * 512];
#pragma unroll
    for (int m = 0; m < 4; ++m)
      af1[m] = *(const short8v*)&lds[sb + aoff + 2048 + m * 512];
    __builtin_amdgcn_s_setprio(1);
#pragma unroll
    for (int m = 0; m < 4; ++m)
#pragma unroll
      for (int n = 0; n < 4; ++n)
        acc[m][n] = __builtin_amdgcn_mfma_f32_16x16x32_bf16(af0[m], bfr[n], acc[m][n], 0, 0, 0);
#pragma unroll
    for (int m = 0; m < 4; ++m)
#pragma unroll
      for (int n = 0; n < 4; ++n)
        acc[4 + m][n] = __builtin_amdgcn_mfma_f32_16x16x32_bf16(af1[m], bfr[n], acc[4 + m][n], 0, 0, 0);
    __builtin_amdgcn_s_setprio(0);
    SCHED;
    if (t < NT - 3)       { asm volatile("s_waitcnt vmcnt(8)"); }
    else if (t == NT - 3) { asm volatile("s_waitcnt vmcnt(4)"); }
    else if (t == NT - 2) { asm volatile("s_waitcnt vmcnt(0)"); }
    SCHED;
    if (t < NT - 1) { SBAR; SCHED; }
  }

  const int crow = m0 + wr * 128 + ((lane >> 4) << 2);
  const int ccol = n0 + wc * 64 + lr;
#pragma unroll
  for (int mi = 0; mi < 8; ++mi)
#pragma unroll
    for (int r = 0; r < 4; ++r) {
      const int row = crow + mi * 16 + r;
#pragma unroll
      for (int n = 0; n < 4; ++n) {
        const int col = ccol + n * 16;
        const float f = acc[mi][n][r];
        const size_t o = (size_t)row * N + col;
        if (EPI == 0) Cf[o] = f;
        else          Ch[o] = f2bf(f);
      }
    }
}

// ---------- row softmax: fp32 (n per row) -> bf16 p ----------
__global__ __launch_bounds__(256) void softmax_rows(
    const float* __restrict__ S, unsigned short* __restrict__ P, int n) {
  const int row = blockIdx.x;
  const int t = threadIdx.x;
  const float4* src = (const float4*)(S + (size_t)row * n);
  float4 v[4];
  float mx = -3.0e38f;
#pragma unroll
  for (int i = 0; i < 4; ++i) {
    v[i] = src[i * 256 + t];
    mx = fmaxf(mx, fmaxf(fmaxf(v[i].x, v[i].y), fmaxf(v[i].z, v[i].w)));
  }
#pragma unroll
  for (int off = 32; off; off >>= 1) mx = fmaxf(mx, __shfl_xor(mx, off));
  __shared__ float redm[4], reds[4];
  const int wid = t >> 6, lane = t & 63;
  if (lane == 0) redm[wid] = mx;
  __syncthreads();
  mx = fmaxf(fmaxf(redm[0], redm[1]), fmaxf(redm[2], redm[3]));
  float sum = 0.f;
#pragma unroll
  for (int i = 0; i < 4; ++i) {
    v[i].x = __expf(v[i].x - mx);
    v[i].y = __expf(v[i].y - mx);
    v[i].z = __expf(v[i].z - mx);
    v[i].w = __expf(v[i].w - mx);
    sum += (v[i].x + v[i].y) + (v[i].z + v[i].w);
  }
#pragma unroll
  for (int off = 32; off; off >>= 1) sum += __shfl_xor(sum, off);
  if (lane == 0) reds[wid] = sum;
  __syncthreads();
  sum = (reds[0] + reds[1]) + (reds[2] + reds[3]);
  float inv = 1.0f / sum;
#pragma unroll
  for (int i = 0; i < 4; ++i) {
    ushort4 o;
    o.x = f2bf(v[i].x * inv);
    o.y = f2bf(v[i].y * inv);
    o.z = f2bf(v[i].z * inv);
    o.w = f2bf(v[i].w * inv);
    *(ushort4*)(P + (size_t)row * n + (size_t)(i * 256 + t) * 4) = o;
  }
}

// ---------- launch ----------
extern "C" void kernel_launch(void* const* d_in, const int* in_sizes, int n_in,
                              void* d_out, int out_size, void* d_ws, size_t ws_size,
                              hipStream_t stream) {
  (void)in_sizes; (void)n_in; (void)out_size; (void)ws_size;
  const float* x  = (const float*)d_in[0];
  const float* Wq = (const float*)d_in[1];
  const float* Wk = (const float*)d_in[2];
  const float* Wv = (const float*)d_in[3];
  const int N = 4096, D = 1024;
  const size_t MB = 1ull << 20;
  char* ws = (char*)d_ws;
  unsigned short* xh  = (unsigned short*)(ws + 0 * MB);     // 8 MB
  unsigned short* xl  = (unsigned short*)(ws + 8 * MB);     // 8 MB
  unsigned short* wqh = (unsigned short*)(ws + 16 * MB);    // 8 MB
  unsigned short* wql = (unsigned short*)(ws + 24 * MB);    // 8 MB
  unsigned short* wkh = (unsigned short*)(ws + 32 * MB);    // 8 MB
  unsigned short* wkl = (unsigned short*)(ws + 40 * MB);    // 8 MB
  unsigned short* wvh = (unsigned short*)(ws + 48 * MB);    // 8 MB
  unsigned short* wvl = (unsigned short*)(ws + 56 * MB);    // 8 MB (written, unused)
  unsigned short* qh  = (unsigned short*)(ws + 64 * MB);    // 32 MB
  unsigned short* ql  = (unsigned short*)(ws + 96 * MB);    // 32 MB
  unsigned short* kh  = (unsigned short*)(ws + 128 * MB);   // 32 MB
  unsigned short* kl  = (unsigned short*)(ws + 160 * MB);   // 32 MB
  unsigned short* vT  = (unsigned short*)(ws + 16 * MB);    // 32 MB, over wq/wk splits (dead)
  unsigned short* p   = (unsigned short*)(ws + 64 * MB);    // 32 MB, over qh (dead)
  float* score = (float*)d_out;
  float* out   = (float*)d_out;

  const unsigned MEL = (unsigned)(MB / 2);   // elements per MB

  // 1) splits
  split_plain<<<(N * D / 4 + 255) / 256, 256, 0, stream>>>(
      (const float4*)x, (ushort4*)xh, (ushort4*)xl, N * D / 4);
  dim3 gT(N / 32, D / 32);
  split_T<<<gT, 256, 0, stream>>>(Wq, wqh, wql, D, N);
  split_T<<<gT, 256, 0, stream>>>(Wk, wkh, wkl, D, N);
  split_T<<<gT, 256, 0, stream>>>(Wv, wvh, wvl, D, N);

  const int GG = (N / 256) * (N / 256);   // 256 workgroups
  // 2) q = x@Wq fused 3-product split -> hi/lo bf16
  //    base=xh; Al=xl(+8MB), Bh=wqh(+16MB), Bl=wql(+24MB)
  gemm_fused3<2><<<GG, 512, 0, stream>>>(xh, 8 * MEL, 16 * MEL, 24 * MEL,
                                         N, D, nullptr, qh, ql);
  // 3) k = x@Wk: Bh=wkh(+32MB), Bl=wkl(+40MB)
  gemm_fused3<2><<<GG, 512, 0, stream>>>(xh, 8 * MEL, 32 * MEL, 40 * MEL,
                                         N, D, nullptr, kh, kl);
  // 4) vT = (x@Wv)^T  (plain bf16, 1-pass)
  gemm_plain<1><<<GG, 512, 0, stream>>>(wvh, xh, N, D, nullptr, vT);
  // 5) score = q@k^T fused, K=4096 -> fp32 d_out
  //    base=qh(+64MB); Al=ql(+96MB->+32), Bh=kh(+128->+64), Bl=kl(+160->+96)
  gemm_fused3<0><<<GG, 512, 0, stream>>>(qh, 32 * MEL, 64 * MEL, 96 * MEL,
                                         N, N, score, nullptr, nullptr);
  // 6) p = softmax(score) -> bf16
  softmax_rows<<<N, 256, 0, stream>>>(score, p, N);
  // 7) out = p @ vT^T -> fp32 d_out
  gemm_plain<0><<<GG, 512, 0, stream>>>(p, vT, N, N, out, nullptr);
}

// Round 9
// 670.247 us; speedup vs baseline: 1.5682x; 1.0299x over previous
//
#include <hip/hip_runtime.h>
#include <hip/hip_bf16.h>
#include <stdint.h>

// ---------- helpers ----------
typedef __attribute__((ext_vector_type(8))) short short8v;   // 8 x bf16 bits (4 VGPRs)
typedef __attribute__((ext_vector_type(4))) float f32x4;

__device__ __forceinline__ unsigned short f2bf(float f) {
  unsigned u = __builtin_bit_cast(unsigned, f);
  unsigned r = 0x7fffu + ((u >> 16) & 1u);          // round-to-nearest-even
  return (unsigned short)((u + r) >> 16);
}
__device__ __forceinline__ float bf2f(unsigned short h) {
  unsigned u = ((unsigned)h) << 16;
  return __builtin_bit_cast(float, u);
}
__device__ __forceinline__ void gload_lds16(const void* g, void* l) {
  __builtin_amdgcn_global_load_lds(
      (const __attribute__((address_space(1))) void*)g,
      (__attribute__((address_space(3))) void*)l, 16, 0, 0);
}
#define SBAR  __builtin_amdgcn_s_barrier()
#define SCHED __builtin_amdgcn_sched_barrier(0)

// ---------- split kernels ----------
__global__ __launch_bounds__(256) void split_plain(
    const float4* __restrict__ X, ushort4* __restrict__ H, ushort4* __restrict__ L, int n4) {
  int idx = blockIdx.x * 256 + threadIdx.x;
  if (idx >= n4) return;
  float4 v = X[idx];
  ushort4 h, l;
  h.x = f2bf(v.x); l.x = f2bf(v.x - bf2f(h.x));
  h.y = f2bf(v.y); l.y = f2bf(v.y - bf2f(h.y));
  h.z = f2bf(v.z); l.z = f2bf(v.z - bf2f(h.z));
  h.w = f2bf(v.w); l.w = f2bf(v.w - bf2f(h.w));
  H[idx] = h; L[idx] = l;
}

__global__ __launch_bounds__(256) void split_T(
    const float* __restrict__ W, unsigned short* __restrict__ H,
    unsigned short* __restrict__ L, int Kd, int Nd) {
  __shared__ float tile[32][33];
  const int t = threadIdx.x;
  const int c = t & 31;
  const int r0 = t >> 5;
  const int k0 = blockIdx.y * 32, n0 = blockIdx.x * 32;
#pragma unroll
  for (int i = 0; i < 4; ++i) {
    int r = r0 + i * 8;
    tile[r][c] = W[(size_t)(k0 + r) * Nd + n0 + c];
  }
  __syncthreads();
#pragma unroll
  for (int i = 0; i < 4; ++i) {
    int n = r0 + i * 8;
    float f = tile[c][n];
    unsigned short h = f2bf(f);
    unsigned short l = f2bf(f - bf2f(h));
    size_t o = (size_t)(n0 + n) * Kd + k0 + c;
    H[o] = h; L[o] = l;
  }
}

// ---------- FUSED split GEMM: C = Ah@Bl^T + Ah@Bh^T + Al@Bh^T ----------
// One base pointer + uniform element offsets (slim addressing, r8-proven).
// 256x256 tile, BK=32, 2-slot ring. Sync skeleton = r6/r7/r8 (tripwire-proven):
// each sub-block {vmcnt(N); SBAR; reads; stage(t+1); MFMA}; stage FIFO
// [Ah,Bl,Bh,Al]; vmcnt 4/6/6 steady, 4/2/0 tail. r9 change: ahf[8] stays
// LIVE across blocks 1-2 (r8's slim addressing freed the regs) -> LDS reads
// drop 32->24 per wave per tile; LDS leaves the critical path.
// EPI 0: fp32 C; 2: split hi/lo bf16.
template<int EPI>
__global__ __launch_bounds__(512, 1) void gemm_fused3(
    const unsigned short* __restrict__ base,            // = Ah
    unsigned dAl, unsigned dBh, unsigned dBl,           // element offsets
    int N, int K,
    float* __restrict__ Cf, unsigned short* __restrict__ Ch, unsigned short* __restrict__ Cl) {
  // 2 slots x [Ah|Bh|Bl|Al] x 8192 ush = 65536 ush = 128 KiB
  __shared__ unsigned short lds[65536];
  const int AH = 0, BH = 8192, BL = 16384, AL = 24576;
  const int NT = K >> 5;
  const int wg = blockIdx.x;
  const int sw = ((wg & 7) << 5) | (wg >> 3);     // XCD-bijective (256 wg)
  const int bx = sw & 15, by = sw >> 4;
  const int m0 = by << 8, n0 = bx << 8;

  const int tid = threadIdx.x;
  const int w = tid >> 6, lane = tid & 63;
  const int wr = w >> 2, wc = w & 3;               // wave tile 128x64
  const int lr = lane & 15;
  // read-side swizzle: phys 16B-slot = logical ^ ((row>>1)&3)
  const int phys = (lane >> 4) ^ ((lr >> 1) & 3);
  const int aoff = (wr * 128 + lr) * 32 + phys * 8;   // + m*512
  const int boff = (wc * 64 + lr) * 32 + phys * 8;    // + n*512
  // stage-side: linear LDS dest, inverse-swizzled global source (Rule 21)
  const int rst = tid >> 2;                            // source row 0..127
  const int ssrc = ((tid & 3) ^ ((tid >> 3) & 3)) * 8; // source k-slot (elements)
  const unsigned jstep = 128u * (unsigned)K;

  const unsigned voffA = (unsigned)(m0 + rst) * (unsigned)K + (unsigned)ssrc;
  const unsigned voffB = (unsigned)(n0 + rst) * (unsigned)K + (unsigned)ssrc;

  f32x4 acc[8][4];
#pragma unroll
  for (int m = 0; m < 8; ++m)
#pragma unroll
    for (int n = 0; n < 4; ++n) acc[m][n] = {0.f, 0.f, 0.f, 0.f};

  // stage one operand subtile (2 gload ops) into slot s for K-tile tt
#define STG2(dsel, vo, loff, s, tt) do {                                     \
    const unsigned o_ = (vo) + (dsel) + (unsigned)(tt) * 32u;                \
    gload_lds16(base + o_,         &lds[(s) + (loff) + (w << 9)]);           \
    gload_lds16(base + o_ + jstep, &lds[(s) + (loff) + 4096 + (w << 9)]);    \
  } while (0)

  // prologue: stage tile 0 into slot 0, FIFO order [Ah, Bl, Bh, Al]  (8 ops)
  STG2(0u,  voffA, AH, 0, 0);
  STG2(dBl, voffB, BL, 0, 0);
  STG2(dBh, voffB, BH, 0, 0);
  STG2(dAl, voffA, AL, 0, 0);

  for (int t = 0; t < NT; ++t) {
    const int slot = (t & 1) << 15;         // *32768
    const int slot1 = ((t + 1) & 1) << 15;
    const bool st = (t + 1) < NT;
    short8v ahf[8];                          // live across blocks 1-2
    // ---- block1 (h,l): certify Ah(t),Bl(t); outstanding 8 -> vmcnt(4) ----
    SCHED; asm volatile("s_waitcnt vmcnt(4)"); SBAR; SCHED;
    {
      short8v bf[4];
#pragma unroll
      for (int n = 0; n < 4; ++n)
        bf[n] = *(const short8v*)&lds[slot + BL + boff + n * 512];
#pragma unroll
      for (int m = 0; m < 8; ++m)
        ahf[m] = *(const short8v*)&lds[slot + AH + aoff + m * 512];
      if (st) { STG2(0u, voffA, AH, slot1, t + 1); STG2(dBl, voffB, BL, slot1, t + 1); }
      __builtin_amdgcn_s_setprio(1);
#pragma unroll
      for (int m = 0; m < 8; ++m)
#pragma unroll
        for (int n = 0; n < 4; ++n)
          acc[m][n] = __builtin_amdgcn_mfma_f32_16x16x32_bf16(ahf[m], bf[n], acc[m][n], 0, 0, 0);
      __builtin_amdgcn_s_setprio(0);
    }
    // ---- block2 (h,h): certify Bh(t); vmcnt(6) steady / (2) tail ----
    SCHED;
    if (st) { asm volatile("s_waitcnt vmcnt(6)"); }
    else    { asm volatile("s_waitcnt vmcnt(2)"); }
    SBAR; SCHED;
    short8v bh[4];                           // lives through block3
    {
#pragma unroll
      for (int n = 0; n < 4; ++n)
        bh[n] = *(const short8v*)&lds[slot + BH + boff + n * 512];
      if (st) { STG2(dBh, voffB, BH, slot1, t + 1); }
      __builtin_amdgcn_s_setprio(1);
#pragma unroll
      for (int m = 0; m < 8; ++m)
#pragma unroll
        for (int n = 0; n < 4; ++n)
          acc[m][n] = __builtin_amdgcn_mfma_f32_16x16x32_bf16(ahf[m], bh[n], acc[m][n], 0, 0, 0);
      __builtin_amdgcn_s_setprio(0);
    }
    // ahf dies here
    // ---- block3 (l,h): certify Al(t); vmcnt(6) steady / (0) tail ----
    SCHED;
    if (st) { asm volatile("s_waitcnt vmcnt(6)"); }
    else    { asm volatile("s_waitcnt vmcnt(0)"); }
    SBAR; SCHED;
    {
      short8v alf[8];
#pragma unroll
      for (int m = 0; m < 8; ++m)
        alf[m] = *(const short8v*)&lds[slot + AL + aoff + m * 512];
      if (st) { STG2(dAl, voffA, AL, slot1, t + 1); }
      __builtin_amdgcn_s_setprio(1);
#pragma unroll
      for (int m = 0; m < 8; ++m)
#pragma unroll
        for (int n = 0; n < 4; ++n)
          acc[m][n] = __builtin_amdgcn_mfma_f32_16x16x32_bf16(alf[m], bh[n], acc[m][n], 0, 0, 0);
      __builtin_amdgcn_s_setprio(0);
    }
    SCHED;
    // no end-of-tile barrier: block1's SBAR of tile t+1 separates the last
    // reads of slot (t-1)&1 from the next writes to it.
  }
#undef STG2

  // epilogue: frag r -> row=(lane>>4)*4+r, col=lane&15  [m89/m91-verified]
  const int crow = m0 + wr * 128 + ((lane >> 4) << 2);
  const int ccol = n0 + wc * 64 + lr;
#pragma unroll
  for (int mi = 0; mi < 8; ++mi)
#pragma unroll
    for (int r = 0; r < 4; ++r) {
      const int row = crow + mi * 16 + r;
#pragma unroll
      for (int n = 0; n < 4; ++n) {
        const int col = ccol + n * 16;
        const float f = acc[mi][n][r];
        const size_t o = (size_t)row * N + col;
        if (EPI == 0) {
          Cf[o] = f;
        } else {
          const unsigned short h = f2bf(f);
          Ch[o] = h;
          Cl[o] = f2bf(f - bf2f(h));
        }
      }
    }
}

// ---------- plain single-pass GEMM (round-2 proven): C = A @ B^T ----------
// 4-deep ring, counted vmcnt 8/4/0 BEFORE the barrier, one SBAR per tile.
// EPI 0: fp32; 1: bf16.
template<int EPI>
__global__ __launch_bounds__(512, 2) void gemm_plain(
    const unsigned short* __restrict__ A, const unsigned short* __restrict__ B,
    int N, int K,
    float* __restrict__ Cf, unsigned short* __restrict__ Ch) {
  __shared__ unsigned short lds[65536];   // 4 slots x (A 8192 + B 8192)
  const int NT = K >> 5;
  const int wg = blockIdx.x;
  const int sw = ((wg & 7) << 5) | (wg >> 3);
  const int bx = sw & 15, by = sw >> 4;
  const int m0 = by << 8, n0 = bx << 8;

  const int tid = threadIdx.x;
  const int w = tid >> 6, lane = tid & 63;
  const int wr = w >> 2, wc = w & 3;
  const int lr = lane & 15;
  const int phys = (lane >> 4) ^ ((lr >> 1) & 3);
  const int aoff = (wr * 128 + lr) * 32 + phys * 8;
  const int boff = 8192 + (wc * 64 + lr) * 32 + phys * 8;
  const int rst = w * 16 + (lane >> 2);
  const int ssrc = ((lane & 3) ^ ((lane >> 3) & 3)) * 8;

  f32x4 acc[8][4];
#pragma unroll
  for (int m = 0; m < 8; ++m)
#pragma unroll
    for (int n = 0; n < 4; ++n) acc[m][n] = {0.f, 0.f, 0.f, 0.f};

  const unsigned short* gA = A + (size_t)(m0 + rst) * K + ssrc;
  const unsigned short* gB = B + (size_t)(n0 + rst) * K + ssrc;
  const size_t jstep = (size_t)128 * K;

  // prologue: stage tiles 0..2 into slots 0..2
#pragma unroll
  for (int tau = 0; tau < 3; ++tau) {
    const int so = tau * 16384 + (w << 9);
    gload_lds16(gA + (size_t)tau * 32, &lds[so]);
    gload_lds16(gA + (size_t)tau * 32 + jstep, &lds[so + 4096]);
    gload_lds16(gB + (size_t)tau * 32, &lds[so + 8192]);
    gload_lds16(gB + (size_t)tau * 32 + jstep, &lds[so + 12288]);
  }
  asm volatile("s_waitcnt vmcnt(8)");
  SCHED; SBAR; SCHED;

  for (int t = 0; t < NT; ++t) {
    const int sb = (t & 3) * 16384;
    if (t + 3 < NT) {
      const int so = ((t + 3) & 3) * 16384 + (w << 9);
      const unsigned short* srcA = gA + (size_t)(t + 3) * 32;
      const unsigned short* srcB = gB + (size_t)(t + 3) * 32;
      gload_lds16(srcA, &lds[so]);
      gload_lds16(srcA + jstep, &lds[so + 4096]);
      gload_lds16(srcB, &lds[so + 8192]);
      gload_lds16(srcB + jstep, &lds[so + 12288]);
    }
    short8v bfr[4], af0[4], af1[4];
#pragma unroll
    for (int n = 0; n < 4; ++n)
      bfr[n] = *(const short8v*)&lds[sb + boff + n * 512];
#pragma unroll
    for (int m = 0; m < 4; ++m)
      af0[m] = *(const short8v*)&lds[sb + aoff + m * 512];
#pragma unroll
    for (int m = 0; m < 4; ++m)
      af1[m] = *(const short8v*)&lds[sb + aoff + 2048 + m * 512];
    __builtin_amdgcn_s_setprio(1);
#pragma unroll
    for (int m = 0; m < 4; ++m)
#pragma unroll
      for (int n = 0; n < 4; ++n)
        acc[m][n] = __builtin_amdgcn_mfma_f32_16x16x32_bf16(af0[m], bfr[n], acc[m][n], 0, 0, 0);
#pragma unroll
    for (int m = 0; m < 4; ++m)
#pragma unroll
      for (int n = 0; n < 4; ++n)
        acc[4 + m][n] = __builtin_amdgcn_mfma_f32_16x16x32_bf16(af1[m], bfr[n], acc[4 + m][n], 0, 0, 0);
    __builtin_amdgcn_s_setprio(0);
    SCHED;
    if (t < NT - 3)       { asm volatile("s_waitcnt vmcnt(8)"); }
    else if (t == NT - 3) { asm volatile("s_waitcnt vmcnt(4)"); }
    else if (t == NT - 2) { asm volatile("s_waitcnt vmcnt(0)"); }
    SCHED;
    if (t < NT - 1) { SBAR; SCHED; }
  }

  const int crow = m0 + wr * 128 + ((lane >> 4) << 2);
  const int ccol = n0 + wc * 64 + lr;
#pragma unroll
  for (int mi = 0; mi < 8; ++mi)
#pragma unroll
    for (int r = 0; r < 4; ++r) {
      const int row = crow + mi * 16 + r;
#pragma unroll
      for (int n = 0; n < 4; ++n) {
        const int col = ccol + n * 16;
        const float f = acc[mi][n][r];
        const size_t o = (size_t)row * N + col;
        if (EPI == 0) Cf[o] = f;
        else          Ch[o] = f2bf(f);
      }
    }
}

// ---------- row softmax: fp32 (n per row) -> bf16 p ----------
__global__ __launch_bounds__(256) void softmax_rows(
    const float* __restrict__ S, unsigned short* __restrict__ P, int n) {
  const int row = blockIdx.x;
  const int t = threadIdx.x;
  const float4* src = (const float4*)(S + (size_t)row * n);
  float4 v[4];
  float mx = -3.0e38f;
#pragma unroll
  for (int i = 0; i < 4; ++i) {
    v[i] = src[i * 256 + t];
    mx = fmaxf(mx, fmaxf(fmaxf(v[i].x, v[i].y), fmaxf(v[i].z, v[i].w)));
  }
#pragma unroll
  for (int off = 32; off; off >>= 1) mx = fmaxf(mx, __shfl_xor(mx, off));
  __shared__ float redm[4], reds[4];
  const int wid = t >> 6, lane = t & 63;
  if (lane == 0) redm[wid] = mx;
  __syncthreads();
  mx = fmaxf(fmaxf(redm[0], redm[1]), fmaxf(redm[2], redm[3]));
  float sum = 0.f;
#pragma unroll
  for (int i = 0; i < 4; ++i) {
    v[i].x = __expf(v[i].x - mx);
    v[i].y = __expf(v[i].y - mx);
    v[i].z = __expf(v[i].z - mx);
    v[i].w = __expf(v[i].w - mx);
    sum += (v[i].x + v[i].y) + (v[i].z + v[i].w);
  }
#pragma unroll
  for (int off = 32; off; off >>= 1) sum += __shfl_xor(sum, off);
  if (lane == 0) reds[wid] = sum;
  __syncthreads();
  sum = (reds[0] + reds[1]) + (reds[2] + reds[3]);
  float inv = 1.0f / sum;
#pragma unroll
  for (int i = 0; i < 4; ++i) {
    ushort4 o;
    o.x = f2bf(v[i].x * inv);
    o.y = f2bf(v[i].y * inv);
    o.z = f2bf(v[i].z * inv);
    o.w = f2bf(v[i].w * inv);
    *(ushort4*)(P + (size_t)row * n + (size_t)(i * 256 + t) * 4) = o;
  }
}

// ---------- launch ----------
extern "C" void kernel_launch(void* const* d_in, const int* in_sizes, int n_in,
                              void* d_out, int out_size, void* d_ws, size_t ws_size,
                              hipStream_t stream) {
  (void)in_sizes; (void)n_in; (void)out_size; (void)ws_size;
  const float* x  = (const float*)d_in[0];
  const float* Wq = (const float*)d_in[1];
  const float* Wk = (const float*)d_in[2];
  const float* Wv = (const float*)d_in[3];
  const int N = 4096, D = 1024;
  const size_t MB = 1ull << 20;
  char* ws = (char*)d_ws;
  unsigned short* xh  = (unsigned short*)(ws + 0 * MB);     // 8 MB
  unsigned short* xl  = (unsigned short*)(ws + 8 * MB);     // 8 MB
  unsigned short* wqh = (unsigned short*)(ws + 16 * MB);    // 8 MB
  unsigned short* wql = (unsigned short*)(ws + 24 * MB);    // 8 MB
  unsigned short* wkh = (unsigned short*)(ws + 32 * MB);    // 8 MB
  unsigned short* wkl = (unsigned short*)(ws + 40 * MB);    // 8 MB
  unsigned short* wvh = (unsigned short*)(ws + 48 * MB);    // 8 MB
  unsigned short* wvl = (unsigned short*)(ws + 56 * MB);    // 8 MB (written, unused)
  unsigned short* qh  = (unsigned short*)(ws + 64 * MB);    // 32 MB
  unsigned short* ql  = (unsigned short*)(ws + 96 * MB);    // 32 MB
  unsigned short* kh  = (unsigned short*)(ws + 128 * MB);   // 32 MB
  unsigned short* kl  = (unsigned short*)(ws + 160 * MB);   // 32 MB
  unsigned short* vT  = (unsigned short*)(ws + 16 * MB);    // 32 MB, over wq/wk splits (dead)
  unsigned short* p   = (unsigned short*)(ws + 64 * MB);    // 32 MB, over qh (dead)
  float* score = (float*)d_out;
  float* out   = (float*)d_out;

  const unsigned MEL = (unsigned)(MB / 2);   // elements per MB

  // 1) splits
  split_plain<<<(N * D / 4 + 255) / 256, 256, 0, stream>>>(
      (const float4*)x, (ushort4*)xh, (ushort4*)xl, N * D / 4);
  dim3 gT(N / 32, D / 32);
  split_T<<<gT, 256, 0, stream>>>(Wq, wqh, wql, D, N);
  split_T<<<gT, 256, 0, stream>>>(Wk, wkh, wkl, D, N);
  split_T<<<gT, 256, 0, stream>>>(Wv, wvh, wvl, D, N);

  const int GG = (N / 256) * (N / 256);   // 256 workgroups
  // 2) q = x@Wq fused 3-product split -> hi/lo bf16
  //    base=xh; Al=xl(+8MB), Bh=wqh(+16MB), Bl=wql(+24MB)
  gemm_fused3<2><<<GG, 512, 0, stream>>>(xh, 8 * MEL, 16 * MEL, 24 * MEL,
                                         N, D, nullptr, qh, ql);
  // 3) k = x@Wk: Bh=wkh(+32MB), Bl=wkl(+40MB)
  gemm_fused3<2><<<GG, 512, 0, stream>>>(xh, 8 * MEL, 32 * MEL, 40 * MEL,
                                         N, D, nullptr, kh, kl);
  // 4) vT = (x@Wv)^T  (plain bf16, 1-pass)
  gemm_plain<1><<<GG, 512, 0, stream>>>(wvh, xh, N, D, nullptr, vT);
  // 5) score = q@k^T fused, K=4096 -> fp32 d_out
  //    base=qh(+64MB); Al=ql(+96MB->+32), Bh=kh(+128->+64), Bl=kl(+160->+96)
  gemm_fused3<0><<<GG, 512, 0, stream>>>(qh, 32 * MEL, 64 * MEL, 96 * MEL,
                                         N, N, score, nullptr, nullptr);
  // 6) p = softmax(score) -> bf16
  softmax_rows<<<N, 256, 0, stream>>>(score, p, N);
  // 7) out = p @ vT^T -> fp32 d_out
  gemm_plain<0><<<GG, 512, 0, stream>>>(p, vT, N, N, out, nullptr);
}